// Round 5
// baseline (1028.598 us; speedup 1.0000x reference)
//
#include <hip/hip_runtime.h>
#include <hip/hip_bf16.h>
#include <math.h>

#define B_ 2
#define S_ 2048
#define D_ 2048
#define H_ 16
#define DH_ 128
#define QP_ 1024
#define KVP_ 1365
#define RD_ 64
#define ND_ 64
#define FF_ 8192
#define T_ (B_*S_)          // 4096 tokens
#define CKW_ (KVP_+RD_)     // 1429
#define KVW_ 3072           // D + H*ND
#define KVP_PAD 1408        // 1365 -> mult of 64
#define CKW_PAD 1536        // 1429 -> mult of 128

typedef __attribute__((ext_vector_type(8))) short short8;
typedef __attribute__((ext_vector_type(4))) short sh4;
typedef __attribute__((ext_vector_type(4))) float floatx4;

__device__ __forceinline__ void gload_lds16(const __hip_bfloat16* g, __hip_bfloat16* l) {
    __builtin_amdgcn_global_load_lds((const __attribute__((address_space(1))) void*)g,
                                     (__attribute__((address_space(3))) void*)l, 16, 0, 0);
}
__device__ __forceinline__ short f2bs(float f) {
    __hip_bfloat16 h = __float2bfloat16(f);
    return *reinterpret_cast<short*>(&h);
}
// XOR-swizzled element offset into a [rows][64] bf16 LDS tile; g = 16B-group (0..7)
__device__ __forceinline__ int sw(int row, int g) { return row * 64 + ((g ^ (row & 7)) << 3); }

// fast gelu: 0.5*v*(1+erf(v/sqrt2)), A&S 7.1.26 erf approx (max err 1.5e-7)
__device__ __forceinline__ float fast_gelu(float v) {
    float x = v * 0.70710678118654752f;
    float ax = fabsf(x);
    float t = __builtin_amdgcn_rcpf(1.f + 0.3275911f * ax);
    float y = t * (0.254829592f + t * (-0.284496736f + t * (1.421413741f + t * (-1.453152027f + t * 1.061405429f))));
    float e = __expf(-ax * ax);
    float erfv = 1.f - y * e;
    erfv = copysignf(erfv, x);
    return 0.5f * v * (1.f + erfv);
}

// ---------------- LayerNorm -> bf16 out with zero-padded stride ----------------
__global__ __launch_bounds__(256) void ln_bf16(const float* __restrict__ in, int in_stride,
                                               const float* __restrict__ w, const float* __restrict__ bb,
                                               __hip_bfloat16* __restrict__ out, int out_stride, int N)
{
    int row = blockIdx.x;
    const float* ip = in + (size_t)row * in_stride;
    __hip_bfloat16* op = out + (size_t)row * out_stride;
    int tid = threadIdx.x;
    __shared__ float s1[256], s2[256];
    float sum = 0.f, sq = 0.f;
    bool vec = (((in_stride | N | out_stride) & 3) == 0);   // block-uniform
    if (vec) {
        const float4* ip4 = (const float4*)ip;
        int n4 = N >> 2;
        for (int i = tid; i < n4; i += 256) {
            float4 v = ip4[i];
            sum += v.x + v.y + v.z + v.w;
            sq  += v.x * v.x + v.y * v.y + v.z * v.z + v.w * v.w;
        }
        s1[tid] = sum; s2[tid] = sq; __syncthreads();
        for (int s = 128; s > 0; s >>= 1) {
            if (tid < s) { s1[tid] += s1[tid + s]; s2[tid] += s2[tid + s]; }
            __syncthreads();
        }
        float mean = s1[0] / N;
        float var  = s2[0] / N - mean * mean;
        float rstd = rsqrtf(var + 1e-5f);
        const float4* w4 = (const float4*)w;
        const float4* b4 = (const float4*)bb;
        for (int i = tid; i < n4; i += 256) {
            float4 v = ip4[i], wv = w4[i], bv = b4[i];
            sh4 o;
            o[0] = f2bs((v.x - mean) * rstd * wv.x + bv.x);
            o[1] = f2bs((v.y - mean) * rstd * wv.y + bv.y);
            o[2] = f2bs((v.z - mean) * rstd * wv.z + bv.z);
            o[3] = f2bs((v.w - mean) * rstd * wv.w + bv.w);
            *(sh4*)&op[i * 4] = o;
        }
    } else {
        for (int i = tid; i < N; i += 256) { float v = ip[i]; sum += v; sq += v * v; }
        s1[tid] = sum; s2[tid] = sq; __syncthreads();
        for (int s = 128; s > 0; s >>= 1) {
            if (tid < s) { s1[tid] += s1[tid + s]; s2[tid] += s2[tid + s]; }
            __syncthreads();
        }
        float mean = s1[0] / N;
        float var  = s2[0] / N - mean * mean;
        float rstd = rsqrtf(var + 1e-5f);
        for (int i = tid; i < N; i += 256) {
            float v = ip[i];
            op[i] = __float2bfloat16((v - mean) * rstd * w[i] + bb[i]);
        }
    }
    for (int i = N + tid; i < out_stride; i += 256) op[i] = __float2bfloat16(0.f);
}

// ---------------- weight transpose + convert: W f32 [K,N] -> Wt bf16 [Npad,Kp] ----------------
__global__ __launch_bounds__(256) void transpose_cvt(const float* __restrict__ W, __hip_bfloat16* __restrict__ Wt,
                                                     int K, int N, int Kp)
{
    __shared__ float t[32][33];
    int k0 = blockIdx.x * 32, n0 = blockIdx.y * 32;
    int tx = threadIdx.x & 31, ty = threadIdx.x >> 5;
    for (int r = ty; r < 32; r += 8) {
        int k = k0 + r, n = n0 + tx;
        t[r][tx] = (k < K && n < N) ? W[(size_t)k * N + n] : 0.f;
    }
    __syncthreads();
    for (int r = ty; r < 32; r += 8) {
        int n = n0 + r, k = k0 + tx;
        Wt[(size_t)n * Kp + k] = __float2bfloat16(t[tx][r]);
    }
}

__global__ __launch_bounds__(256) void cvt_bf16(const float* __restrict__ in, __hip_bfloat16* __restrict__ out, int n)
{
    int i = blockIdx.x * 256 + threadIdx.x;
    if (i < n) out[i] = __float2bfloat16(in[i]);
}

// ---------------- bf16 MFMA GEMM (m97 structure + XOR-swizzled LDS + XCD swizzle) ----------------
template<int EPI, typename CT>
__global__ __launch_bounds__(256) void gemm_bf16(const __hip_bfloat16* __restrict__ A,
                                                 const __hip_bfloat16* __restrict__ Bt,
                                                 CT* __restrict__ C, int M, int N, int Kp, int ldc,
                                                 const float* __restrict__ bias,
                                                 const float* __restrict__ resid)
{
    __shared__ __hip_bfloat16 As[128 * 64];
    __shared__ __hip_bfloat16 Bs[128 * 64];
    int tid = threadIdx.x;
    int gx = gridDim.x;
    int nwg = gx * gridDim.y;
    int o = blockIdx.y * gx + blockIdx.x;
    int sId = ((nwg & 7) == 0) ? ((o & 7) * (nwg >> 3) + (o >> 3)) : o;
    int bm = (sId / gx) * 128;
    int bn = (sId % gx) * 128;
    int wid = tid >> 6, lane = tid & 63;
    int wm = (wid >> 1) * 64, wn = (wid & 1) * 64;
    int lrow = lane & 15;
    int quad = lane >> 4;

    floatx4 acc[4][4];
    #pragma unroll
    for (int i = 0; i < 4; ++i)
        #pragma unroll
        for (int j = 0; j < 4; ++j)
            acc[i][j] = (floatx4){0.f, 0.f, 0.f, 0.f};

    for (int k0 = 0; k0 < Kp; k0 += 64) {
        #pragma unroll
        for (int it = 0; it < 4; ++it) {
            int chunk = it * 256 + tid;
            int row = chunk >> 3, g = chunk & 7;
            int col = (g ^ (row & 7)) << 3;
            gload_lds16(A + (size_t)(bm + row) * Kp + k0 + col, &As[chunk * 8]);
        }
        #pragma unroll
        for (int it = 0; it < 4; ++it) {
            int chunk = it * 256 + tid;
            int row = chunk >> 3, g = chunk & 7;
            int col = (g ^ (row & 7)) << 3;
            gload_lds16(Bt + (size_t)(bn + row) * Kp + k0 + col, &Bs[chunk * 8]);
        }
        __syncthreads();
        #pragma unroll
        for (int kk = 0; kk < 2; ++kk) {       // k-group s = kk*4 + quad
            short8 a[4], b[4];
            #pragma unroll
            for (int i = 0; i < 4; ++i)
                a[i] = *(const short8*)&As[sw(wm + i * 16 + lrow, kk * 4 + quad)];
            #pragma unroll
            for (int j = 0; j < 4; ++j)
                b[j] = *(const short8*)&Bs[sw(wn + j * 16 + lrow, kk * 4 + quad)];
            #pragma unroll
            for (int i = 0; i < 4; ++i)
                #pragma unroll
                for (int j = 0; j < 4; ++j)
                    acc[i][j] = __builtin_amdgcn_mfma_f32_16x16x32_bf16(a[i], b[j], acc[i][j], 0, 0, 0);
        }
        __syncthreads();
    }

    int cq4 = quad * 4;
    #pragma unroll
    for (int i = 0; i < 4; ++i) {
        #pragma unroll
        for (int j = 0; j < 4; ++j) {
            int col = bn + wn + j * 16 + lrow;
            if (col >= N) continue;
            #pragma unroll
            for (int r = 0; r < 4; ++r) {
                int rowg = bm + wm + i * 16 + cq4 + r;
                float v = acc[i][j][r];
                size_t idx = (size_t)rowg * ldc + col;
                if (EPI == 1) v += resid[idx];
                if (EPI == 2) { v += bias[col]; v = fast_gelu(v); }
                if (EPI == 3) { v += bias[col]; v += ((const float*)C)[idx]; }
                C[idx] = (CT)v;
            }
        }
    }
}

#define BARP() __builtin_amdgcn_s_barrier()
#define SCBP() __builtin_amdgcn_sched_barrier(0)
#define GATEP(nw) asm volatile("s_waitcnt vmcnt(" #nw ")" ::: "memory")

// ---------------- 256x128 cross-phase-pipelined bf16 MFMA GEMM ----------------
// (round-4 kernel, kept for W_uq / W_o where 256^2 grids would under-fill)
template<int EPI, typename CT>
__global__ __launch_bounds__(512, 1) void gemm_pp(const __hip_bfloat16* __restrict__ A,
                                                  const __hip_bfloat16* __restrict__ Bt,
                                                  CT* __restrict__ C, int M, int N, int Kp, int ldc,
                                                  const float* __restrict__ bias,
                                                  const float* __restrict__ resid)
{
    __shared__ __hip_bfloat16 As[3][16384];   // [buf][256 rows * 64]
    __shared__ __hip_bfloat16 Bs[3][8192];    // [buf][128 rows * 64]

    int tid = threadIdx.x;
    int wid = tid >> 6, lane = tid & 63;
    int lrow = lane & 15, quad = lane >> 4;
    int awm = (wid >> 1) * 64;                // 4 M-positions
    int bwn = (wid & 1) * 64;                 // 2 N-positions

    int gx = gridDim.x;
    int nwg = gx * gridDim.y;
    int o = blockIdx.y * gx + blockIdx.x;
    int q8 = nwg >> 3, r8 = nwg & 7;
    int xcd = o & 7, oi = o >> 3;
    int s = (xcd < r8 ? xcd * (q8 + 1) : r8 * (q8 + 1) + (xcd - r8) * q8) + oi;
    int bm = (s / gx) * 256, bn = (s % gx) * 128;

    const __hip_bfloat16* Abm = A  + (size_t)bm * Kp;
    const __hip_bfloat16* Bbn = Bt + (size_t)bn * Kp;

    int drow = tid >> 3;
    int csw  = ((tid & 7) ^ (drow & 7)) << 3;
    int ldst = tid * 8;

#define PSTAGE_A(k0v, dst) do { \
    gload_lds16(Abm + (size_t)drow * Kp + (k0v) + csw,         (dst) + ldst); \
    gload_lds16(Abm + (size_t)(drow + 64) * Kp + (k0v) + csw,  (dst) + 4096 + ldst); \
    gload_lds16(Abm + (size_t)(drow + 128) * Kp + (k0v) + csw, (dst) + 8192 + ldst); \
    gload_lds16(Abm + (size_t)(drow + 192) * Kp + (k0v) + csw, (dst) + 12288 + ldst); \
  } while (0)
#define PSTAGE_B(k0v, dst) do { \
    gload_lds16(Bbn + (size_t)drow * Kp + (k0v) + csw,        (dst) + ldst); \
    gload_lds16(Bbn + (size_t)(drow + 64) * Kp + (k0v) + csw, (dst) + 4096 + ldst); \
  } while (0)

    int k0off = ((quad       ^ (lrow & 7)) << 3);
    int k1off = (((4 + quad) ^ (lrow & 7)) << 3);

    short8 af0[4], af1[4], bf0[4], bf1[4];
    floatx4 acc[4][4];
    #pragma unroll
    for (int m = 0; m < 4; ++m)
        #pragma unroll
        for (int n = 0; n < 4; ++n)
            acc[m][n] = (floatx4){0.f, 0.f, 0.f, 0.f};

#define PREAD(bufA, bufB, dA, dB, koff) do { \
    _Pragma("unroll") \
    for (int m = 0; m < 4; ++m) \
      dA[m] = *(const short8*)((bufA) + (awm + m * 16 + lrow) * 64 + (koff)); \
    _Pragma("unroll") \
    for (int n = 0; n < 4; ++n) \
      dB[n] = *(const short8*)((bufB) + (bwn + n * 16 + lrow) * 64 + (koff)); \
  } while (0)

#define PMFMA(fa, fb) do { \
    __builtin_amdgcn_s_setprio(1); \
    _Pragma("unroll") \
    for (int m = 0; m < 4; ++m) \
      _Pragma("unroll") \
      for (int n = 0; n < 4; ++n) \
        acc[m][n] = __builtin_amdgcn_mfma_f32_16x16x32_bf16(fa[m], fb[n], acc[m][n], 0, 0, 0); \
    __builtin_amdgcn_s_setprio(0); \
  } while (0)

    __hip_bfloat16 *aC = &As[0][0], *aN = &As[1][0], *aS = &As[2][0];
    __hip_bfloat16 *bC = &Bs[0][0], *bN = &Bs[1][0], *bS = &Bs[2][0];

    int NT = Kp >> 6;

    PSTAGE_A(0, aC);  PSTAGE_B(0, bC);
    PSTAGE_A(64, aN); PSTAGE_B(64, bN);
    GATEP(6); SCBP(); BARP(); SCBP();
    PREAD(aC, bC, af0, bf0, k0off);

    #pragma unroll 1
    for (int t = 0; t < NT; ++t) {
        int ks = ((t + 2 < NT) ? t + 2 : NT - 1) << 6;
        PSTAGE_A(ks, aS); PSTAGE_B(ks, bS);
        PREAD(aC, bC, af1, bf1, k1off);
        PMFMA(af0, bf0);
        GATEP(6); SCBP(); BARP(); SCBP();
        PREAD(aN, bN, af0, bf0, k0off);
        PMFMA(af1, bf1);
        SCBP(); BARP(); SCBP();
        __hip_bfloat16* ta = aC; aC = aN; aN = aS; aS = ta;
        __hip_bfloat16* tb = bC; bC = bN; bN = bS; bS = tb;
    }
    asm volatile("s_waitcnt vmcnt(0)" ::: "memory");

    int cq4 = quad * 4;
    #pragma unroll
    for (int m = 0; m < 4; ++m) {
        int rowg = bm + awm + m * 16 + cq4;
        #pragma unroll
        for (int n = 0; n < 4; ++n) {
            int col = bn + bwn + n * 16 + lrow;
            #pragma unroll
            for (int r = 0; r < 4; ++r) {
                float v = acc[m][n][r];
                size_t idx = (size_t)(rowg + r) * ldc + col;
                if (EPI == 1) v += resid[idx];
                if (EPI == 2) { v += bias[col]; v = fast_gelu(v); }
                if (EPI == 3) { v += bias[col]; v += ((const float*)C)[idx]; }
                C[idx] = (CT)v;
            }
        }
    }
#undef PSTAGE_A
#undef PSTAGE_B
#undef PREAD
#undef PMFMA
}

// ---------------- 256x256 pp GEMM (A read-ahead, B phase-local; 160 KiB LDS) ----------------
// Round-4 model: LDS read bytes/MFMA is the binding resource. 256^2 tile: 192 KB
// reads per 512 MFMA (0.375 KB/MFMA, under the MFMA line) vs 256x128's 0.5.
// Buffers: A triple (aC=t, aN=t+1, aS=stage t+2), B double (b[t&1]=t, b[(t+1)&1]).
// Per tile: stage {A(t+2):4, B(t+1):4}; GATE(8) drains {A(t+1),B(t)} (1 tile flight);
// BAR; read B(t)kk0(local)+A(t)kk1(ahead); MFMA(kk0); read B(t)kk1+A(t+1)kk0(ahead);
// MFMA(kk1); BAR. Write-after-read safety: every slot's last read is lgkm-consumed
// before this tile's end-BAR, and its restage is issued after that BAR (aS = A(t)
// slot restaged at t+1; b[(t+1)&1] = B(t-1) slot, dead since t-1). Cross-wave
// visibility of stages: own-wave GATE + BAR. SCB around BARs pins motion.
// Optional split-K via gridDim.z: koff = z*Klen, C += z*M*ldc.
template<int EPI, typename CT>
__global__ __launch_bounds__(512, 1) void gemm_pp2(const __hip_bfloat16* __restrict__ A,
                                                   const __hip_bfloat16* __restrict__ Bt,
                                                   CT* __restrict__ C, int M, int N, int Klen,
                                                   int lda, int ldb, int ldc,
                                                   const float* __restrict__ bias,
                                                   const float* __restrict__ resid)
{
    __shared__ __hip_bfloat16 As[3][16384];   // 3 x 32 KiB
    __shared__ __hip_bfloat16 Bs[2][16384];   // 2 x 32 KiB  -> 160 KiB total

    int tid = threadIdx.x;
    int wid = tid >> 6, lane = tid & 63;
    int lrow = lane & 15, quad = lane >> 4;
    int awm = (wid >> 2) * 128;               // 2 M-halves
    int bwn = (wid & 3) * 64;                 // 4 N-quarters

    // bijective XCD swizzle within the z-plane
    int gx = gridDim.x;
    int nwg = gx * gridDim.y;
    int o = blockIdx.y * gx + blockIdx.x;
    int q8 = nwg >> 3, r8 = nwg & 7;
    int xcd = o & 7, oi = o >> 3;
    int s = (xcd < r8 ? xcd * (q8 + 1) : r8 * (q8 + 1) + (xcd - r8) * q8) + oi;
    int bm = (s / gx) * 256, bn = (s % gx) * 256;
    int koff = blockIdx.z * Klen;
    C += (size_t)blockIdx.z * M * ldc;

    const __hip_bfloat16* Abm = A  + (size_t)bm * lda + koff;
    const __hip_bfloat16* Bbn = Bt + (size_t)bn * ldb + koff;

    int drow = tid >> 3;
    int csw  = ((tid & 7) ^ (drow & 7)) << 3;
    int ldst = tid * 8;

#define P2STAGE(base, ld, k0v, dst) do { \
    gload_lds16((base) + (size_t)drow * (ld) + (k0v) + csw,         (dst) + ldst); \
    gload_lds16((base) + (size_t)(drow + 64) * (ld) + (k0v) + csw,  (dst) + 4096 + ldst); \
    gload_lds16((base) + (size_t)(drow + 128) * (ld) + (k0v) + csw, (dst) + 8192 + ldst); \
    gload_lds16((base) + (size_t)(drow + 192) * (ld) + (k0v) + csw, (dst) + 12288 + ldst); \
  } while (0)

    int k0off = ((quad       ^ (lrow & 7)) << 3);
    int k1off = (((4 + quad) ^ (lrow & 7)) << 3);

    short8 af0[8], af1[8], bf[4];
    floatx4 acc[8][4];
    #pragma unroll
    for (int m = 0; m < 8; ++m)
        #pragma unroll
        for (int n = 0; n < 4; ++n)
            acc[m][n] = (floatx4){0.f, 0.f, 0.f, 0.f};

#define P2READ_A(buf, dst, kof) do { \
    _Pragma("unroll") \
    for (int m = 0; m < 8; ++m) \
      dst[m] = *(const short8*)((buf) + (awm + m * 16 + lrow) * 64 + (kof)); \
  } while (0)
#define P2READ_B(buf, kof) do { \
    _Pragma("unroll") \
    for (int n = 0; n < 4; ++n) \
      bf[n] = *(const short8*)((buf) + (bwn + n * 16 + lrow) * 64 + (kof)); \
  } while (0)
#define P2MFMA(fa) do { \
    __builtin_amdgcn_s_setprio(1); \
    _Pragma("unroll") \
    for (int m = 0; m < 8; ++m) \
      _Pragma("unroll") \
      for (int n = 0; n < 4; ++n) \
        acc[m][n] = __builtin_amdgcn_mfma_f32_16x16x32_bf16(fa[m], bf[n], acc[m][n], 0, 0, 0); \
    __builtin_amdgcn_s_setprio(0); \
  } while (0)

    __hip_bfloat16 *aC = &As[0][0], *aN = &As[1][0], *aS = &As[2][0];

    int NT = Klen >> 6;

    // prologue: A(0), B(0), A(1); GATE(4) drains A(0),B(0) leaving A(1) in flight
    P2STAGE(Abm, lda, 0,  aC);
    P2STAGE(Bbn, ldb, 0,  &Bs[0][0]);
    P2STAGE(Abm, lda, 64, aN);
    GATEP(4); SCBP(); BARP(); SCBP();
    P2READ_A(aC, af0, k0off);      // kk0 of tile 0

    #pragma unroll 1
    for (int t = 0; t < NT; ++t) {
        int kA = ((t + 2 < NT) ? t + 2 : NT - 1) << 6;   // clamped: staged, never read
        int kB = ((t + 1 < NT) ? t + 1 : NT - 1) << 6;
        __hip_bfloat16* bR = &Bs[t & 1][0];
        __hip_bfloat16* bT = &Bs[(t + 1) & 1][0];
        P2STAGE(Abm, lda, kA, aS);
        P2STAGE(Bbn, ldb, kB, bT);
        GATEP(8); SCBP(); BARP(); SCBP();
        P2READ_B(bR, k0off);           // local kk0(t)
        P2READ_A(aC, af1, k1off);      // ahead kk1(t)
        P2MFMA(af0);                   // 32 MFMA (waits bf only)
        P2READ_B(bR, k1off);           // local kk1(t)
        P2READ_A(aN, af0, k0off);      // ahead kk0(t+1)
        P2MFMA(af1);
        SCBP(); BARP(); SCBP();
        __hip_bfloat16* ta = aC; aC = aN; aN = aS; aS = ta;
    }
    asm volatile("s_waitcnt vmcnt(0)" ::: "memory");

    int cq4 = quad * 4;
    #pragma unroll
    for (int m = 0; m < 8; ++m) {
        int rowg = bm + awm + m * 16 + cq4;
        #pragma unroll
        for (int n = 0; n < 4; ++n) {
            int col = bn + bwn + n * 16 + lrow;
            #pragma unroll
            for (int r = 0; r < 4; ++r) {
                float v = acc[m][n][r];
                size_t idx = (size_t)(rowg + r) * ldc + col;
                if (EPI == 1) v += resid[idx];
                if (EPI == 2) { v += bias[col]; v = fast_gelu(v); }
                if (EPI == 3) { v += bias[col]; v += ((const float*)C)[idx]; }
                C[idx] = (CT)v;
            }
        }
    }
#undef P2STAGE
#undef P2READ_A
#undef P2READ_B
#undef P2MFMA
}

// ---------------- split-K reduce for W2: out0 += P0 + P1 + b2 ----------------
__global__ __launch_bounds__(256) void reduce_w2(float* __restrict__ out0,
                                                 const float* __restrict__ P,
                                                 const float* __restrict__ b2)
{
    const float4* P0 = (const float4*)P;
    const float4* P1 = (const float4*)(P + (size_t)T_ * D_);
    const float4* bv = (const float4*)b2;
    float4* o4 = (float4*)out0;
    int n4 = (T_ * D_) >> 2;
    for (int i = blockIdx.x * 256 + threadIdx.x; i < n4; i += gridDim.x * 256) {
        float4 a = P0[i], b = P1[i], c = o4[i], d = bv[i & ((D_ >> 2) - 1)];
        c.x += a.x + b.x + d.x;
        c.y += a.y + b.y + d.y;
        c.z += a.z + b.z + d.z;
        c.w += a.w + b.w + d.w;
        o4[i] = c;
    }
}

// ---------------- RoPE ----------------
__global__ __launch_bounds__(256) void rope_q_kernel(float* __restrict__ Q)
{
    int idx = blockIdx.x * 256 + threadIdx.x;        // T*H*32
    int i = idx & 31;
    int h = (idx >> 5) & (H_ - 1);
    int t = idx >> 9;
    float f = expf(-(float)i * (9.210340371976184f / 64.0f));
    float ang = (float)(t & (S_ - 1)) * f;
    float sv, cv; sincosf(ang, &sv, &cv);
    float* p = Q + (size_t)t * D_ + h * DH_ + ND_;
    float u = p[i], v = p[i + 32];
    p[i]      = u * cv - v * sv;
    p[i + 32] = v * cv + u * sv;
}

__global__ __launch_bounds__(256) void rope_kr_bf(const float* __restrict__ ckv, __hip_bfloat16* __restrict__ kr)
{
    int idx = blockIdx.x * 256 + threadIdx.x;        // T*32
    int i = idx & 31;
    int t = idx >> 5;
    float f = expf(-(float)i * (9.210340371976184f / 64.0f));
    float ang = (float)(t & (S_ - 1)) * f;
    float sv, cv; sincosf(ang, &sv, &cv);
    const float* src = ckv + (size_t)t * CKW_ + KVP_;
    float u = src[i], v = src[i + 32];
    kr[(size_t)t * RD_ + i]      = __float2bfloat16(u * cv - v * sv);
    kr[(size_t)t * RD_ + i + 32] = __float2bfloat16(v * cv + u * sv);
}

// ---------------- V transpose: kvu[t][h*192+64+v] -> Vt[b*H+h][v][t] (bf16) ----------------
__global__ __launch_bounds__(256) void vt_pack(const __hip_bfloat16* __restrict__ kvu,
                                               __hip_bfloat16* __restrict__ Vt)
{
    int bh = blockIdx.y; int b = bh >> 4, h = bh & 15;
    int v = threadIdx.x & 127;
    int tg = blockIdx.x * 2 + (threadIdx.x >> 7);
    int t0 = tg * 8;
    short8 o;
    #pragma unroll
    for (int j = 0; j < 8; ++j) {
        __hip_bfloat16 e = kvu[(size_t)(b * S_ + t0 + j) * KVW_ + h * 192 + 64 + v];
        o[j] = *reinterpret_cast<short*>(&e);
    }
    *(short8*)&Vt[((size_t)bh * 128 + v) * S_ + t0] = o;
}

// ---------------- Flash MFMA attention (+ XCD chunk swizzle: same bh -> same XCD) ----
__global__ __launch_bounds__(256) void attn_mfma(const float* __restrict__ Q,
                                                 const __hip_bfloat16* __restrict__ KVU,
                                                 const __hip_bfloat16* __restrict__ KR,
                                                 const __hip_bfloat16* __restrict__ VT,
                                                 __hip_bfloat16* __restrict__ O)
{
    __shared__ __hip_bfloat16 Kls[64 * 64];
    __shared__ __hip_bfloat16 Krls[64 * 64];
    __shared__ __hip_bfloat16 Vls[128 * 64];
    __shared__ __hip_bfloat16 Pls[4 * 32 * 64];

    int tid = threadIdx.x, wid = tid >> 6, lane = tid & 63;
    int lrow = lane & 15, quad = lane >> 4;
    int kq8 = quad * 8;
    int o = blockIdx.y * 16 + blockIdx.x;
    int sId = (o & 7) * 64 + (o >> 3);
    int qtile = 15 - (sId & 15);
    int bh = sId >> 4;
    int b = bh >> 4, h = bh & 15;
    int q0 = qtile * 128, wq = wid * 32;

    const float scale = 0.08838834764831845f;

    short8 bq[2][2], bqr[2][2];
    #pragma unroll
    for (int n = 0; n < 2; ++n) {
        const float* qrow = Q + (size_t)(b * S_ + q0 + wq + n * 16 + lrow) * D_ + h * DH_;
        #pragma unroll
        for (int s = 0; s < 2; ++s) {
            int base = s * 32 + kq8;
            #pragma unroll
            for (int j = 0; j < 8; ++j) {
                bq[n][s][j]  = f2bs(qrow[base + j] * scale);
                bqr[n][s][j] = f2bs(qrow[64 + base + j] * scale);
            }
        }
    }

    float mstate[2] = {-INFINITY, -INFINITY};
    float lstate[2] = {0.f, 0.f};
    floatx4 acco[8][2];
    #pragma unroll
    for (int vt = 0; vt < 8; ++vt)
        #pragma unroll
        for (int n = 0; n < 2; ++n)
            acco[vt][n] = (floatx4){0.f, 0.f, 0.f, 0.f};

    int nk = qtile * 2 + 2;
    int qmax_w = q0 + wq + 31;

    for (int kt = 0; kt < nk; ++kt) {
        int k0 = kt * 64;
        #pragma unroll
        for (int it = 0; it < 2; ++it) {
            int c = it * 256 + tid;
            int row = c >> 3, g = c & 7;
            int col = ((g ^ (row & 7)) << 3);
            gload_lds16(KVU + (size_t)(b * S_ + k0 + row) * KVW_ + h * 192 + col, &Kls[c * 8]);
            gload_lds16(KR + (size_t)(b * S_ + k0 + row) * RD_ + col, &Krls[c * 8]);
        }
        #pragma unroll
        for (int it = 0; it < 4; ++it) {
            int c = it * 256 + tid;
            int row = c >> 3, g = c & 7;
            int col = ((g ^ (row & 7)) << 3);
            gload_lds16(VT + ((size_t)bh * 128 + row) * S_ + k0 + col, &Vls[c * 8]);
        }
        __syncthreads();

        if (k0 <= qmax_w) {
            floatx4 sacc[4][2];
            #pragma unroll
            for (int m = 0; m < 4; ++m)
                #pragma unroll
                for (int n = 0; n < 2; ++n)
                    sacc[m][n] = (floatx4){0.f, 0.f, 0.f, 0.f};
            #pragma unroll
            for (int m = 0; m < 4; ++m) {
                short8 ak[2], akr[2];
                #pragma unroll
                for (int s = 0; s < 2; ++s) {
                    ak[s]  = *(const short8*)&Kls[sw(m * 16 + lrow, s * 4 + quad)];
                    akr[s] = *(const short8*)&Krls[sw(m * 16 + lrow, s * 4 + quad)];
                }
                #pragma unroll
                for (int n = 0; n < 2; ++n)
                    #pragma unroll
                    for (int s = 0; s < 2; ++s) {
                        sacc[m][n] = __builtin_amdgcn_mfma_f32_16x16x32_bf16(ak[s],  bq[n][s],  sacc[m][n], 0, 0, 0);
                        sacc[m][n] = __builtin_amdgcn_mfma_f32_16x16x32_bf16(akr[s], bqr[n][s], sacc[m][n], 0, 0, 0);
                    }
            }
            #pragma unroll
            for (int n = 0; n < 2; ++n) {
                int qg = q0 + wq + n * 16 + lrow;
                float tmax = -INFINITY;
                #pragma unroll
                for (int m = 0; m < 4; ++m)
                    #pragma unroll
                    for (int r = 0; r < 4; ++r) {
                        int kg = k0 + m * 16 + quad * 4 + r;
                        if (kg > qg) sacc[m][n][r] = -1e30f;
                        tmax = fmaxf(tmax, sacc[m][n][r]);
                    }
                tmax = fmaxf(tmax, __shfl_xor(tmax, 16));
                tmax = fmaxf(tmax, __shfl_xor(tmax, 32));
                float mnew = fmaxf(mstate[n], tmax);
                float alpha = __expf(mstate[n] - mnew);
                mstate[n] = mnew;
                float ps = 0.f;
                #pragma unroll
                for (int m = 0; m < 4; ++m) {
                    sh4 pk;
                    #pragma unroll
                    for (int r = 0; r < 4; ++r) {
                        float p = __expf(sacc[m][n][r] - mnew);
                        ps += p;
                        pk[r] = f2bs(p);
                    }
                    int qloc = n * 16 + lrow;
                    int off = wid * 2048 + qloc * 64 + (((m * 2 + (quad >> 1)) ^ (lrow & 7)) << 3) + ((quad & 1) << 2);
                    *(sh4*)&Pls[off] = pk;
                }
                ps += __shfl_xor(ps, 16);
                ps += __shfl_xor(ps, 32);
                lstate[n] = lstate[n] * alpha + ps;
                #pragma unroll
                for (int vt = 0; vt < 8; ++vt)
                    #pragma unroll
                    for (int r = 0; r < 4; ++r)
                        acco[vt][n][r] *= alpha;
            }
            short8 bp[2][2];
            #pragma unroll
            for (int n = 0; n < 2; ++n)
                #pragma unroll
                for (int s = 0; s < 2; ++s)
                    bp[n][s] = *(const short8*)&Pls[wid * 2048 + sw(n * 16 + lrow, s * 4 + quad)];
            #pragma unroll
            for (int vt = 0; vt < 8; ++vt) {
                short8 av[2];
                #pragma unroll
                for (int s = 0; s < 2; ++s)
                    av[s] = *(const short8*)&Vls[sw(vt * 16 + lrow, s * 4 + quad)];
                #pragma unroll
                for (int n = 0; n < 2; ++n)
                    #pragma unroll
                    for (int s = 0; s < 2; ++s)
                        acco[vt][n] = __builtin_amdgcn_mfma_f32_16x16x32_bf16(av[s], bp[n][s], acco[vt][n], 0, 0, 0);
            }
        }
        __syncthreads();
    }

    #pragma unroll
    for (int n = 0; n < 2; ++n) {
        float inv = 1.0f / lstate[n];
        int tok = b * S_ + q0 + wq + n * 16 + lrow;
        #pragma unroll
        for (int vt = 0; vt < 8; ++vt) {
            sh4 o4;
            #pragma unroll
            for (int r = 0; r < 4; ++r) o4[r] = f2bs(acco[vt][n][r] * inv);
            *(sh4*)&O[(size_t)tok * D_ + h * DH_ + vt * 16 + quad * 4] = o4;
        }
    }
}

// ---------------- Launcher ----------------
extern "C" void kernel_launch(void* const* d_in, const int* in_sizes, int n_in,
                              void* d_out, int out_size, void* d_ws, size_t ws_size,
                              hipStream_t stream)
{
    const float* x     = (const float*)d_in[0];
    const float* anw   = (const float*)d_in[1];
    const float* anb   = (const float*)d_in[2];
    const float* W_dq  = (const float*)d_in[3];
    const float* qlw   = (const float*)d_in[4];
    const float* qlb   = (const float*)d_in[5];
    const float* W_uq  = (const float*)d_in[6];
    const float* W_dkv = (const float*)d_in[7];
    const float* kvlw  = (const float*)d_in[8];
    const float* kvlb  = (const float*)d_in[9];
    const float* W_ukv = (const float*)d_in[10];
    const float* W_o   = (const float*)d_in[11];
    const float* fnw   = (const float*)d_in[12];
    const float* fnb   = (const float*)d_in[13];
    const float* W1    = (const float*)d_in[14];
    const float* b1    = (const float*)d_in[15];
    const float* W2    = (const float*)d_in[16];
    const float* b2    = (const float*)d_in[17];

    float* out0 = (float*)d_out;                     // [T, D]
    float* ckv  = out0 + (size_t)T_ * D_;            // [T, 1429]

    float* ws = (float*)d_ws;
    float* Q  = ws;                                          // [T,2048] f32
    float* cq = Q + (size_t)T_ * D_;                         // [T,1024] f32
    __hip_bfloat16* kvu_bf = (__hip_bfloat16*)(cq + (size_t)T_ * QP_);  // [T,3072]
    __hip_bfloat16* kr_bf  = kvu_bf + (size_t)T_ * KVW_;     // [T,64]
    __hip_bfloat16* Vt     = kr_bf + (size_t)T_ * RD_;       // [B*H][128][S]  (16 MB)
    __hip_bfloat16* h_bf   = Vt + (size_t)T_ * D_;           // [T,2048]       (16 MB)
    __hip_bfloat16* cq_bf  = h_bf + (size_t)T_ * D_;         // [T,1024]       (8 MB)
    __hip_bfloat16* kvl_bf = cq_bf + (size_t)T_ * QP_;       // [T,1408]       (11 MB)
    __hip_bfloat16* o_bf   = kvl_bf + (size_t)T_ * KVP_PAD;  // [T,2048]       (16 MB)
    __hip_bfloat16* wdq_t  = o_bf + (size_t)T_ * D_;         // [1024,2048]
    __hip_bfloat16* wuq_t  = wdq_t + (size_t)QP_ * D_;       // [2048,1024]
    __hip_bfloat16* wdkv_t = wuq_t + (size_t)D_ * QP_;       // [1536,2048]
    __hip_bfloat16* wukv_t = wdkv_t + (size_t)CKW_PAD * D_;  // [3072,1408]
    __hip_bfloat16* wo_b   = wukv_t + (size_t)KVW_ * KVP_PAD;// [2048,2048]
    __hip_bfloat16* w1_t   = wo_b + (size_t)D_ * D_;         // [8192,2048]
    __hip_bfloat16* w2_t   = w1_t + (size_t)FF_ * D_;        // [2048,8192]
    __hip_bfloat16* ff1_bf = (__hip_bfloat16*)ws;            // overlays Q+cq+kvu (dead by FFN)
    // W2 split-K partials: 64 MB over [Vt .. o_bf) — all dead by W2 time
    float* Pw2 = (float*)Vt;

    dim3 blk(256);
    dim3 blk8(512);

    { dim3 g(D_ / 32, QP_ / 32);       transpose_cvt<<<g, blk, 0, stream>>>(W_dq,  wdq_t,  D_, QP_, D_); }
    { dim3 g(QP_ / 32, D_ / 32);       transpose_cvt<<<g, blk, 0, stream>>>(W_uq,  wuq_t,  QP_, D_, QP_); }
    { dim3 g(D_ / 32, CKW_PAD / 32);   transpose_cvt<<<g, blk, 0, stream>>>(W_dkv, wdkv_t, D_, CKW_, D_); }
    { dim3 g(KVP_PAD / 32, KVW_ / 32); transpose_cvt<<<g, blk, 0, stream>>>(W_ukv, wukv_t, KVP_, KVW_, KVP_PAD); }
    { int n = D_ * D_;                 cvt_bf16<<<(n + 255) / 256, blk, 0, stream>>>(W_o, wo_b, n); }
    { dim3 g(D_ / 32, FF_ / 32);       transpose_cvt<<<g, blk, 0, stream>>>(W1, w1_t, D_, FF_, D_); }
    { dim3 g(FF_ / 32, D_ / 32);       transpose_cvt<<<g, blk, 0, stream>>>(W2, w2_t, FF_, D_, FF_); }

    ln_bf16<<<T_, blk, 0, stream>>>(x, D_, anw, anb, h_bf, D_, D_);
    { dim3 g(QP_ / 128, T_ / 128);   // 256 blocks at 128^2
      gemm_bf16<0, float><<<g, blk, 0, stream>>>(h_bf, wdq_t, cq, T_, QP_, D_, QP_, nullptr, nullptr); }
    ln_bf16<<<T_, blk, 0, stream>>>(cq, QP_, qlw, qlb, cq_bf, QP_, QP_);
    { dim3 g(D_ / 128, T_ / 256);    // 256 blocks
      gemm_pp<0, float><<<g, blk8, 0, stream>>>(cq_bf, wuq_t, Q, T_, D_, QP_, D_, nullptr, nullptr); }
    rope_q_kernel<<<(T_ * H_ * 32) / 256, blk, 0, stream>>>(Q);
    { dim3 g(CKW_PAD / 128, T_ / 128);  // 384 blocks at 128^2
      gemm_bf16<0, float><<<g, blk, 0, stream>>>(h_bf, wdkv_t, ckv, T_, CKW_, D_, CKW_, nullptr, nullptr); }
    ln_bf16<<<T_, blk, 0, stream>>>(ckv, CKW_, kvlw, kvlb, kvl_bf, KVP_PAD, KVP_);
    { dim3 g(KVW_ / 256, T_ / 256);  // 192 blocks at 256^2
      gemm_pp2<0, __hip_bfloat16><<<g, blk8, 0, stream>>>(kvl_bf, wukv_t, kvu_bf, T_, KVW_,
                                                          KVP_PAD, KVP_PAD, KVP_PAD, KVW_, nullptr, nullptr); }
    rope_kr_bf<<<(T_ * 32) / 256, blk, 0, stream>>>(ckv, kr_bf);
    { dim3 g(S_ / 16, B_ * H_);
      vt_pack<<<g, blk, 0, stream>>>(kvu_bf, Vt); }
    { dim3 g(16, B_ * H_);
      attn_mfma<<<g, blk, 0, stream>>>(Q, kvu_bf, kr_bf, Vt, o_bf); }
    { dim3 g(D_ / 128, T_ / 256);    // 256 blocks (pp-128: 256^2 would be half-chip)
      gemm_pp<1, float><<<g, blk8, 0, stream>>>(o_bf, wo_b, out0, T_, D_, D_, D_, nullptr, x); }
    ln_bf16<<<T_, blk, 0, stream>>>(out0, D_, fnw, fnb, h_bf, D_, D_);
    { dim3 g(FF_ / 256, T_ / 256);   // 512 blocks at 256^2
      gemm_pp2<2, __hip_bfloat16><<<g, blk8, 0, stream>>>(h_bf, w1_t, ff1_bf, T_, FF_,
                                                          D_, D_, D_, FF_, b1, nullptr); }
    { dim3 g(D_ / 256, T_ / 256, 2); // 8x16x2 = 256 blocks, split-K=2 into partials
      gemm_pp2<0, float><<<g, blk8, 0, stream>>>(ff1_bf, w2_t, Pw2, T_, D_,
                                                 FF_ / 2, FF_, FF_, D_, nullptr, nullptr); }
    reduce_w2<<<1024, blk, 0, stream>>>(out0, Pw2, b2);
}